// Round 4
// baseline (160.029 us; speedup 1.0000x reference)
//
#include <hip/hip_runtime.h>
#include <hip/hip_fp16.h>
#include <cstdint>
#include <cmath>

// Problem constants
#define NB 2
#define NC 256
#define HW 2304          // 48*48
#define HID 64
#define OH 96
#define OW 96
#define N1 9216          // 96*96
#define SCALE_ATTN 0.17677669529663689f   // 32^-0.5
#define RESZ ((float)(47.0/95.0))

// oc-group split for k4: 8 waves, counts {3,3,2,2,2,2,2,2}
__device__ __host__ inline int ocb8(int w) { return w < 2 ? 3 * w : 6 + 2 * (w - 2); }
__device__ __host__ inline int cnt8(int w) { return w < 2 ? 3 : 2; }

// ---------------- KA: fused prep.
__global__ void kA_prep(const float* __restrict__ x, const float* __restrict__ Wq,
                        const float* __restrict__ Wk, const float* __restrict__ off_w,
                        const float* __restrict__ dw_w, const float* __restrict__ off_b,
                        __half* __restrict__ v_nhwc, float* __restrict__ WT4,
                        float* __restrict__ dwT, float* __restrict__ wg2,
                        float* __restrict__ bsg2) {
    int blk = blockIdx.x;
    if (blk < 1152) {
        int pt = blk % 72;
        int t2 = blk / 72;
        int ct = t2 & 3;
        int bg = t2 >> 2;
        int b = bg >> 1, g = bg & 1;
        __shared__ float tile[32][33];
        int tx = threadIdx.x & 31, row = threadIdx.x >> 5;   // row 0..7
#pragma unroll
        for (int r = 0; r < 4; r++) {
            int c = ct * 32 + row + r * 8;
            tile[row + r * 8][tx] = x[((size_t)(b * 256 + g * 128 + c)) * HW + pt * 32 + tx];
        }
        __syncthreads();
#pragma unroll
        for (int r = 0; r < 4; r++) {
            int p = pt * 32 + row + r * 8;
            v_nhwc[((size_t)bg * HW + p) * 128 + ct * 32 + tx] =
                __float2half(tile[tx][row + r * 8]);
        }
    } else {
        int idx = (blk - 1152) * 256 + threadIdx.x;
        if (idx < 32768) {
            int c = idx >> 7, t = idx & 127;
            float v = (t < 64) ? Wq[t * 256 + c] : Wk[(t - 64) * 256 + c];
            WT4[(((size_t)(c >> 2) * 128) + t) * 4 + (c & 3)] = v;
        } else if (idx < 32768 + 288) {
            int i = idx - 32768;
            int wi = i >> 5, c = i & 31;
            dwT[i] = dw_w[c * 9 + wi];
        } else if (idx < 32768 + 288 + 8 * 288 * 3) {
            int i = idx - (32768 + 288);
            int w = i / 864, r = i - w * 864;
            int kk = r / 3, j = r - kk * 3;
            wg2[i] = (j < cnt8(w)) ? off_w[(ocb8(w) + j) * 288 + kk] : 0.f;
        } else if (idx < 32768 + 288 + 8 * 288 * 3 + 24) {
            int i = idx - (32768 + 288 + 8 * 288 * 3);
            int w = i / 3, j = i - w * 3;
            bsg2[i] = (j < cnt8(w)) ? off_b[ocb8(w) + j] : 0.f;
        }
    }
}

// ---------------- K1: channel LN over 256 + Q/K projection.
__global__ __launch_bounds__(512) void k1_ln_qk(const __half* __restrict__ v_nhwc,
                         const float* __restrict__ ln_g, const float* __restrict__ ln_b,
                         const float* __restrict__ WT4,
                         float* __restrict__ q_pix, __half* __restrict__ k_nhwc) {
    int blk = blockIdx.x;            // 0..575
    int tid = threadIdx.x;
    int wv = tid >> 6, lane = tid & 63;
    __shared__ float xs[8][256];
    {
        int pix = blk * 8 + wv;
        int b = pix / HW, p = pix - b * HW;
        int c0 = lane * 2;
        __half2 h0 = *(const __half2*)(v_nhwc + (((size_t)(b * 2 + 0) * HW) + p) * 128 + c0);
        __half2 h1 = *(const __half2*)(v_nhwc + (((size_t)(b * 2 + 1) * HW) + p) * 128 + c0);
        float2 u0 = __half22float2(h0);
        float2 u1 = __half22float2(h1);
        float s = u0.x + u0.y + u1.x + u1.y;
#pragma unroll
        for (int off = 1; off < 64; off <<= 1) s += __shfl_xor(s, off);
        float mu = s * (1.f / 256.f);
        float d0 = u0.x - mu, d1 = u0.y - mu, d2 = u1.x - mu, d3 = u1.y - mu;
        float q = d0 * d0 + d1 * d1 + d2 * d2 + d3 * d3;
#pragma unroll
        for (int off = 1; off < 64; off <<= 1) q += __shfl_xor(q, off);
        float rs = rsqrtf(q * (1.f / 256.f) + 1e-5f);
        float2 w0, w1;
        w0.x = d0 * rs * ln_g[c0] + ln_b[c0];
        w0.y = d1 * rs * ln_g[c0 + 1] + ln_b[c0 + 1];
        w1.x = d2 * rs * ln_g[128 + c0] + ln_b[128 + c0];
        w1.y = d3 * rs * ln_g[129 + c0] + ln_b[129 + c0];
        *(float2*)&xs[wv][c0] = w0;
        *(float2*)&xs[wv][128 + c0] = w1;
    }
    __syncthreads();
    int o = tid & 127, ph = tid >> 7;     // ph 0..3, handles pixels 2ph, 2ph+1
    float a0 = 0.f, a1 = 0.f;
    const float4* wp = (const float4*)WT4 + o;         // stride 128 float4s per c4
    const float4* xa = (const float4*)xs[ph * 2];
    const float4* xb4 = (const float4*)xs[ph * 2 + 1];
#pragma unroll 8
    for (int c4 = 0; c4 < 64; c4++) {
        float4 w = wp[(size_t)c4 * 128];
        float4 p0 = xa[c4], p1 = xb4[c4];
        a0 += w.x * p0.x + w.y * p0.y + w.z * p0.z + w.w * p0.w;
        a1 += w.x * p1.x + w.y * p1.y + w.z * p1.z + w.w * p1.w;
    }
#pragma unroll
    for (int k = 0; k < 2; k++) {
        int pix = blk * 8 + ph * 2 + k;
        int b = pix / HW, p = pix - b * HW;
        float a = k ? a1 : a0;
        if (o < 64) {
            q_pix[(((size_t)b * HW) + p) * 64 + o] = a;
        } else {
            int t = o - 64, g = t >> 5, c32 = t & 31;
            k_nhwc[(((size_t)(b * 2 + g) * HW) + p) * 32 + c32] = __float2half(a);
        }
    }
}

// ---------------- K3: t = GELU(LN(dw3x3(resize(q)))). Thread per (bg, pixel, ch).
// Center tap (dy=0,dx=0) IS the resized q at this pixel -> store it to qr for k5.
__global__ __launch_bounds__(256) void k3_t(const float* __restrict__ q_pix,
                                            const float* __restrict__ dwT,
                                            const float* __restrict__ og,
                                            const float* __restrict__ ob,
                                            __half* __restrict__ tbuf_h,
                                            float* __restrict__ qr) {
    int gid = blockIdx.x * 256 + threadIdx.x;   // 4*9216*32
    int c = gid & 31;
    int p2 = gid >> 5;                          // bg*9216 + p
    int bg = p2 / N1, p = p2 - bg * N1;
    int b = bg >> 1, g = bg & 1;
    int oy = p / OW, ox = p - oy * OW;
    const float* qb = q_pix + ((size_t)b * HW) * 64 + g * 32 + c;
    float acc = 0.f;
    float qcen = 0.f;
#pragma unroll
    for (int dy = -1; dy <= 1; dy++) {
        int yy = oy + dy;
        if ((unsigned)yy >= (unsigned)OH) continue;
        float ysf = yy * RESZ;
        int y0 = min((int)ysf, 46);
        float wy = ysf - (float)y0;
#pragma unroll
        for (int dx = -1; dx <= 1; dx++) {
            int xx = ox + dx;
            if ((unsigned)xx >= (unsigned)OW) continue;
            float xsf = xx * RESZ;
            int x0 = min((int)xsf, 46);
            float wx = xsf - (float)x0;
            int i00 = (y0 * 48 + x0) * 64;
            float q00 = qb[i00], q01 = qb[i00 + 64];
            float q10 = qb[i00 + 48 * 64], q11 = qb[i00 + 49 * 64];
            float qv = (q00 * (1.f - wy) + q10 * wy) * (1.f - wx)
                     + (q01 * (1.f - wy) + q11 * wy) * wx;
            acc += qv * dwT[((dy + 1) * 3 + dx + 1) * 32 + c];
            if (dy == 0 && dx == 0) qcen = qv;
        }
    }
    float s = acc;
#pragma unroll
    for (int off = 1; off < 32; off <<= 1) s += __shfl_xor(s, off);
    float mu = s * (1.f / 32.f);
    float d = acc - mu;
    float v = d * d;
#pragma unroll
    for (int off = 1; off < 32; off <<= 1) v += __shfl_xor(v, off);
    float rsv = rsqrtf(v * (1.f / 32.f) + 1e-5f);
    float t = d * rsv * og[c] + ob[c];
    float ge = 0.5f * t * (1.f + erff(t * 0.70710678118654752f));
    tbuf_h[(size_t)p2 * 32 + c] = __float2half(ge);
    qr[((size_t)b * N1 + p) * 64 + g * 32 + c] = qcen;
}

// ---------------- K4: conv 3x3 32->18 + bias.
__global__ __launch_bounds__(512) void k4_pred(const __half* __restrict__ tbuf_h,
                                               const float* __restrict__ wg2,
                                               const float* __restrict__ bsg2,
                                               float* __restrict__ pred) {
    int blk = blockIdx.x;
    int bg = blk / 144, tile = blk - bg * 144;
    int ty0 = (tile / 12) * 8, tx0 = (tile % 12) * 8;
    int tid = threadIdx.x;
    __shared__ float ts[100 * 33];   // [halo point][ic], pitch 33

    const __half* tb = tbuf_h + (size_t)bg * N1 * 32;
    for (int item = tid; item < 400; item += 512) {
        int pt = item >> 2, qg = item & 3;       // 8 channels per item
        int hy = ty0 + pt / 10 - 1;
        int hx = tx0 + pt % 10 - 1;
        float4 raw = make_float4(0.f, 0.f, 0.f, 0.f);
        if ((unsigned)hy < (unsigned)OH && (unsigned)hx < (unsigned)OW)
            raw = *(const float4*)(tb + ((size_t)(hy * OW + hx)) * 32 + qg * 8);
        const __half2* h2 = (const __half2*)&raw;
        int base = pt * 33 + qg * 8;
#pragma unroll
        for (int i = 0; i < 4; i++) {
            float2 f = __half22float2(h2[i]);
            ts[base + i * 2] = f.x;
            ts[base + i * 2 + 1] = f.y;
        }
    }
    __syncthreads();

    int w = __builtin_amdgcn_readfirstlane(tid >> 6);
    int lane = tid & 63;
    int y = lane >> 3, x = lane & 7;
    int ocb = ocb8(w), cnt = cnt8(w);
    float acc[3];
#pragma unroll
    for (int j = 0; j < 3; j++) acc[j] = bsg2[w * 3 + j];
    const float* tsb = &ts[(y * 10 + x) * 33];
    const float* wgp = wg2 + (size_t)w * 864;
    const int kof[9] = {0, 33, 66, 330, 363, 396, 660, 693, 726};
    for (int ic = 0; ic < 32; ic++) {
#pragma unroll
        for (int k = 0; k < 9; k++) {
            float tv = tsb[kof[k] + ic];
            const float* wr = wgp + (ic * 9 + k) * 3;
#pragma unroll
            for (int j = 0; j < 3; j++) acc[j] += tv * wr[j];
        }
    }
    int p = (ty0 + y) * OW + tx0 + x;
    float* pp = pred + ((size_t)bg * N1 + p) * 18 + ocb;
#pragma unroll
    for (int j = 0; j < 3; j++)
        if (j < cnt) pp[j] = acc[j];
}

// ---------------- K5: deformable attention. 1 wave = 2 consecutive pixels (same row);
// block = 8 pixels (4 waves). Lane remap: c2 = lane&15, jg = lane>>4.
// NEW: this lane's 6 taps (wts+cof) batch-loaded from LDS into registers once,
// then score AND value phases run entirely out of registers (no per-iter LDS).
__global__ __launch_bounds__(256) void k5_attn(const float* __restrict__ pred,
                                               const float* __restrict__ qr,
                                               const __half* __restrict__ k_nhwc,
                                               const __half* __restrict__ v_nhwc,
                                               const float* __restrict__ rpb,
                                               float* __restrict__ out) {
    int tid = threadIdx.x;
    int wv = __builtin_amdgcn_readfirstlane(tid >> 6);
    int lane = tid & 63;
    int gp = blockIdx.x * 8;               // block-base pixel (same bg, same row)
    int bg = gp / N1, p0 = gp % N1;
    int b = bg >> 1, g = bg & 1;
    int pw = p0 + wv * 2;                  // wave-base pixel
    int oy = pw / OW, ox0 = pw % OW;

    __shared__ float4 wts[4][2][9];        // [wave][px][tap] corner weights
    __shared__ int4   cof[4][2][9];        // [wave][px][tap] corner pixel offsets
    __shared__ float  outb[4][2][128];     // [wave][px][ch]

    // --- tap setup: lanes 0..17 -> (px, j)   (round-0 proven form)
    if (lane < 18) {
        int px = lane / 9, j = lane % 9;
        int p = pw + px;
        int ky = j / 3, kx = j % 3;
        const float* pp = pred + ((size_t)bg * N1 + p) * 18;
        float pr0 = pp[j * 2];
        float pr1 = pp[j * 2 + 1];
        float th0 = 1.f - 2.f * __builtin_amdgcn_rcpf(__expf(2.f * pr0) + 1.f);
        float th1 = 1.f - 2.f * __builtin_amdgcn_rcpf(__expf(2.f * pr1) + 1.f);
        float py  = th0 * 11.0f + (float)(ky - 1) + (float)oy;
        float pxc = th1 * 11.0f + (float)(kx - 1) + (float)(ox0 + px);
        float iy = py * RESZ, ix = pxc * RESZ;
        float y0f = floorf(iy), x0f = floorf(ix);
        float wy = iy - y0f, wx = ix - x0f;
        int y0 = (int)y0f, x0 = (int)x0f;
        bool vy0 = (unsigned)y0 < 48u, vy1 = (unsigned)(y0 + 1) < 48u;
        bool vx0 = (unsigned)x0 < 48u, vx1 = (unsigned)(x0 + 1) < 48u;
        int y0c = min(max(y0, 0), 47), y1c = min(max(y0 + 1, 0), 47);
        int x0c = min(max(x0, 0), 47), x1c = min(max(x0 + 1, 0), 47);
        float4 w;
        w.x = (vy0 && vx0) ? (1.f - wy) * (1.f - wx) : 0.f;
        w.y = (vy0 && vx1) ? (1.f - wy) * wx : 0.f;
        w.z = (vy1 && vx0) ? wy * (1.f - wx) : 0.f;
        w.w = (vy1 && vx1) ? wy * wx : 0.f;
        wts[wv][px][j] = w;
        cof[wv][px][j] = make_int4(y0c * 48 + x0c, y0c * 48 + x1c,
                                   y1c * 48 + x0c, y1c * 48 + x1c);
    }
    __syncthreads();

    int c2 = lane & 15, jg = lane >> 4;    // channel pair 0..15, tap group 0..3

    // --- batch register cache of this lane's taps: one dense LDS burst
    float4 tw[2][3];
    int4   tc[2][3];
#pragma unroll
    for (int px = 0; px < 2; px++) {
#pragma unroll
        for (int jj = 0; jj < 3; jj++) {
            int j = jj * 4 + jg;
            if (j < 9) {
                tw[px][jj] = wts[wv][px][j];
                tc[px][jj] = cof[wv][px][j];
            } else {
                tw[px][jj] = make_float4(0.f, 0.f, 0.f, 0.f);
                tc[px][jj] = make_int4(0, 0, 0, 0);
            }
        }
    }

    const __half* kb = k_nhwc + (size_t)bg * HW * 32 + 2 * c2;
    const float* rb = rpb + (size_t)g * 288;
    const __half* vb = v_nhwc + (size_t)bg * HW * 128 + c2 * 8;

    // rpb pairs for this lane's taps (j = jj*4 + jg)
    float2 rv[3];
#pragma unroll
    for (int jj = 0; jj < 3; jj++) {
        int j = jj * 4 + jg;
        rv[jj] = (j < 9) ? *(const float2*)(rb + j * 32 + 2 * c2) : make_float2(0.f, 0.f);
    }

    // qv pairs for both px from materialized resized q
    const float* qrb = qr + ((size_t)b * N1 + pw) * 64 + g * 32 + 2 * c2;
    float2 qv[2];
    {
        float2 t0 = *(const float2*)qrb;
        float2 t1 = *(const float2*)(qrb + 64);
        qv[0] = make_float2(t0.x * SCALE_ATTN, t0.y * SCALE_ATTN);
        qv[1] = make_float2(t1.x * SCALE_ATTN, t1.y * SCALE_ATTN);
    }

    // --- scores: 2 px x 3 jj, half2 K loads, reduce over 16 c2 lanes
    float s[2][3];
#pragma unroll
    for (int px = 0; px < 2; px++) {
#pragma unroll
        for (int jj = 0; jj < 3; jj++) {
            int j = jj * 4 + jg;
            float partial = 0.f;
            if (j < 9) {
                float4 w = tw[px][jj];
                int4 co = tc[px][jj];
                float2 k0 = __half22float2(*(const __half2*)(kb + (size_t)co.x * 32));
                float2 k1 = __half22float2(*(const __half2*)(kb + (size_t)co.y * 32));
                float2 k2 = __half22float2(*(const __half2*)(kb + (size_t)co.z * 32));
                float2 k3 = __half22float2(*(const __half2*)(kb + (size_t)co.w * 32));
                float kvx = w.x * k0.x + w.y * k1.x + w.z * k2.x + w.w * k3.x;
                float kvy = w.x * k0.y + w.y * k1.y + w.z * k2.y + w.w * k3.y;
                partial = qv[px].x * (kvx + rv[jj].x) + qv[px].y * (kvy + rv[jj].y);
            }
#pragma unroll
            for (int off = 1; off < 16; off <<= 1) partial += __shfl_xor(partial, off);
            s[px][jj] = (j < 9) ? partial : -1e30f;
        }
    }

    // --- softmax per px; reduce across the 4 tap groups (xor16, xor32)
    float pj[2][3];
#pragma unroll
    for (int px = 0; px < 2; px++) {
        float m = fmaxf(fmaxf(s[px][0], s[px][1]), s[px][2]);
        m = fmaxf(m, __shfl_xor(m, 16));
        m = fmaxf(m, __shfl_xor(m, 32));
        float e0 = __expf(s[px][0] - m);
        float e1 = __expf(s[px][1] - m);
        float e2 = __expf(s[px][2] - m);
        float sum = e0 + e1 + e2;
        sum += __shfl_xor(sum, 16);
        sum += __shfl_xor(sum, 32);
        float inv = __builtin_amdgcn_rcpf(sum);
        pj[px][0] = e0 * inv; pj[px][1] = e1 * inv; pj[px][2] = e2 * inv;
    }

    // --- value phase: 16B V loads (8 channels/lane), packed __hfma2 accumulation
    __half2 acc[2][4];
#pragma unroll
    for (int px = 0; px < 2; px++)
#pragma unroll
        for (int q = 0; q < 4; q++) acc[px][q] = __float2half2_rn(0.f);

#pragma unroll
    for (int px = 0; px < 2; px++) {
#pragma unroll
        for (int jj = 0; jj < 3; jj++) {
            int j = jj * 4 + jg;
            if (j < 9) {
                float p = pj[px][jj];
                float4 w = tw[px][jj];
                int4 co = tc[px][jj];
                float4 r0 = *(const float4*)(vb + (size_t)co.x * 128);
                float4 r1 = *(const float4*)(vb + (size_t)co.y * 128);
                float4 r2 = *(const float4*)(vb + (size_t)co.z * 128);
                float4 r3 = *(const float4*)(vb + (size_t)co.w * 128);
                const __half2* A0 = (const __half2*)&r0;
                const __half2* A1 = (const __half2*)&r1;
                const __half2* A2 = (const __half2*)&r2;
                const __half2* A3 = (const __half2*)&r3;
                __half2 f0 = __float2half2_rn(w.x * p);
                __half2 f1 = __float2half2_rn(w.y * p);
                __half2 f2 = __float2half2_rn(w.z * p);
                __half2 f3 = __float2half2_rn(w.w * p);
#pragma unroll
                for (int q = 0; q < 4; q++) {
                    acc[px][q] = __hfma2(f0, A0[q], acc[px][q]);
                    acc[px][q] = __hfma2(f1, A1[q], acc[px][q]);
                    acc[px][q] = __hfma2(f2, A2[q], acc[px][q]);
                    acc[px][q] = __hfma2(f3, A3[q], acc[px][q]);
                }
            }
        }
    }

    // --- output: cvt to float, reduce across tap groups in float, write LDS
#pragma unroll
    for (int px = 0; px < 2; px++) {
        float f[8];
#pragma unroll
        for (int q = 0; q < 4; q++) {
            float2 t = __half22float2(acc[px][q]);
            f[2 * q] = t.x; f[2 * q + 1] = t.y;
        }
#pragma unroll
        for (int i = 0; i < 8; i++) {
            f[i] += __shfl_xor(f[i], 16);
            f[i] += __shfl_xor(f[i], 32);
        }
        if (lane < 16) {
            *(float4*)&outb[wv][px][c2 * 8]     = make_float4(f[0], f[1], f[2], f[3]);
            *(float4*)&outb[wv][px][c2 * 8 + 4] = make_float4(f[4], f[5], f[6], f[7]);
        }
    }
    __syncthreads();

    // final write: thread t: ch = t&127, qh = t>>7 -> float4 covering px qh*4..qh*4+3
    {
        int ch = tid & 127, qh = tid >> 7;
        float* op = out + ((size_t)b * NC + g * 128 + ch) * N1 + p0 + qh * 4;
        float4 v4 = make_float4(outb[qh * 2][0][ch], outb[qh * 2][1][ch],
                                outb[qh * 2 + 1][0][ch], outb[qh * 2 + 1][1][ch]);
        *(float4*)op = v4;
    }
}

extern "C" void kernel_launch(void* const* d_in, const int* in_sizes, int n_in,
                              void* d_out, int out_size, void* d_ws, size_t ws_size,
                              hipStream_t stream) {
    const float* x      = (const float*)d_in[0];
    const float* ln_g   = (const float*)d_in[1];
    const float* ln_b   = (const float*)d_in[2];
    const float* Wq     = (const float*)d_in[3];
    const float* Wk     = (const float*)d_in[4];
    const float* dw_w   = (const float*)d_in[5];
    const float* off_g  = (const float*)d_in[6];
    const float* off_bt = (const float*)d_in[7];
    const float* off_w  = (const float*)d_in[8];
    const float* off_b  = (const float*)d_in[9];
    const float* rpb    = (const float*)d_in[10];
    float* out = (float*)d_out;

    // Workspace layout. fp32 region then fp16 region then qr. ~14 MB. NO aliasing.
    float* ws = (float*)d_ws;
    float* WT4    = ws;                       // 32768   [64][128][4]
    float* q_pix  = WT4 + 32768;              // 294912  [2][2304][64]
    float* pred   = q_pix + 294912;           // 663552  [4][9216][18]
    float* dwT    = pred + 663552;            // 288     [9][32]
    float* wg2    = dwT + 288;                // 6912    [8][288][3]
    float* bsg2   = wg2 + 6912;               // 24      [8][3]
    __half* v_nhwc = (__half*)(bsg2 + 24);    // 1179648 h [4][2304][128]
    __half* k_nhwc = v_nhwc + 1179648;        // 294912 h  [4][2304][32]
    __half* tbuf_h = k_nhwc + 294912;         // 1179648 h [4][9216][32]
    float* qr      = (float*)(tbuf_h + 1179648); // 1179648 f [2][9216][64]

    kA_prep<<<1309, 256, 0, stream>>>(x, Wq, Wk, off_w, dw_w, off_b,
                                      v_nhwc, WT4, dwT, wg2, bsg2);
    k1_ln_qk<<<576, 512, 0, stream>>>(v_nhwc, ln_g, ln_b, WT4, q_pix, k_nhwc);
    k3_t<<<4608, 256, 0, stream>>>(q_pix, dwT, off_g, off_bt, tbuf_h, qr);
    k4_pred<<<576, 512, 0, stream>>>(tbuf_h, wg2, bsg2, pred);
    k5_attn<<<4608, 256, 0, stream>>>(pred, qr, k_nhwc, v_nhwc, rpb, out);
}

// Round 5
// 159.886 us; speedup vs baseline: 1.0009x; 1.0009x over previous
//
#include <hip/hip_runtime.h>
#include <hip/hip_fp16.h>
#include <cstdint>
#include <cmath>

// Problem constants
#define NB 2
#define NC 256
#define HW 2304          // 48*48
#define HID 64
#define OH 96
#define OW 96
#define N1 9216          // 96*96
#define SCALE_ATTN 0.17677669529663689f   // 32^-0.5
#define RESZ ((float)(47.0/95.0))

// oc-group split for k4: 8 waves, counts {3,3,2,2,2,2,2,2}
__device__ __host__ inline int ocb8(int w) { return w < 2 ? 3 * w : 6 + 2 * (w - 2); }
__device__ __host__ inline int cnt8(int w) { return w < 2 ? 3 : 2; }

// ---------------- KA: fused prep.
__global__ void kA_prep(const float* __restrict__ x, const float* __restrict__ Wq,
                        const float* __restrict__ Wk, const float* __restrict__ off_w,
                        const float* __restrict__ dw_w, const float* __restrict__ off_b,
                        __half* __restrict__ v_nhwc, float* __restrict__ WT4,
                        float* __restrict__ dwT, float* __restrict__ wg2,
                        float* __restrict__ bsg2) {
    int blk = blockIdx.x;
    if (blk < 1152) {
        int pt = blk % 72;
        int t2 = blk / 72;
        int ct = t2 & 3;
        int bg = t2 >> 2;
        int b = bg >> 1, g = bg & 1;
        __shared__ float tile[32][33];
        int tx = threadIdx.x & 31, row = threadIdx.x >> 5;   // row 0..7
#pragma unroll
        for (int r = 0; r < 4; r++) {
            int c = ct * 32 + row + r * 8;
            tile[row + r * 8][tx] = x[((size_t)(b * 256 + g * 128 + c)) * HW + pt * 32 + tx];
        }
        __syncthreads();
#pragma unroll
        for (int r = 0; r < 4; r++) {
            int p = pt * 32 + row + r * 8;
            v_nhwc[((size_t)bg * HW + p) * 128 + ct * 32 + tx] =
                __float2half(tile[tx][row + r * 8]);
        }
    } else {
        int idx = (blk - 1152) * 256 + threadIdx.x;
        if (idx < 32768) {
            int c = idx >> 7, t = idx & 127;
            float v = (t < 64) ? Wq[t * 256 + c] : Wk[(t - 64) * 256 + c];
            WT4[(((size_t)(c >> 2) * 128) + t) * 4 + (c & 3)] = v;
        } else if (idx < 32768 + 288) {
            int i = idx - 32768;
            int wi = i >> 5, c = i & 31;
            dwT[i] = dw_w[c * 9 + wi];
        } else if (idx < 32768 + 288 + 8 * 288 * 3) {
            int i = idx - (32768 + 288);
            int w = i / 864, r = i - w * 864;
            int kk = r / 3, j = r - kk * 3;
            wg2[i] = (j < cnt8(w)) ? off_w[(ocb8(w) + j) * 288 + kk] : 0.f;
        } else if (idx < 32768 + 288 + 8 * 288 * 3 + 24) {
            int i = idx - (32768 + 288 + 8 * 288 * 3);
            int w = i / 3, j = i - w * 3;
            bsg2[i] = (j < cnt8(w)) ? off_b[ocb8(w) + j] : 0.f;
        }
    }
}

// ---------------- K1: channel LN over 256 + Q/K projection.
__global__ __launch_bounds__(512) void k1_ln_qk(const __half* __restrict__ v_nhwc,
                         const float* __restrict__ ln_g, const float* __restrict__ ln_b,
                         const float* __restrict__ WT4,
                         float* __restrict__ q_pix, __half* __restrict__ k_nhwc) {
    int blk = blockIdx.x;            // 0..575
    int tid = threadIdx.x;
    int wv = tid >> 6, lane = tid & 63;
    __shared__ float xs[8][256];
    {
        int pix = blk * 8 + wv;
        int b = pix / HW, p = pix - b * HW;
        int c0 = lane * 2;
        __half2 h0 = *(const __half2*)(v_nhwc + (((size_t)(b * 2 + 0) * HW) + p) * 128 + c0);
        __half2 h1 = *(const __half2*)(v_nhwc + (((size_t)(b * 2 + 1) * HW) + p) * 128 + c0);
        float2 u0 = __half22float2(h0);
        float2 u1 = __half22float2(h1);
        float s = u0.x + u0.y + u1.x + u1.y;
#pragma unroll
        for (int off = 1; off < 64; off <<= 1) s += __shfl_xor(s, off);
        float mu = s * (1.f / 256.f);
        float d0 = u0.x - mu, d1 = u0.y - mu, d2 = u1.x - mu, d3 = u1.y - mu;
        float q = d0 * d0 + d1 * d1 + d2 * d2 + d3 * d3;
#pragma unroll
        for (int off = 1; off < 64; off <<= 1) q += __shfl_xor(q, off);
        float rs = rsqrtf(q * (1.f / 256.f) + 1e-5f);
        float2 w0, w1;
        w0.x = d0 * rs * ln_g[c0] + ln_b[c0];
        w0.y = d1 * rs * ln_g[c0 + 1] + ln_b[c0 + 1];
        w1.x = d2 * rs * ln_g[128 + c0] + ln_b[128 + c0];
        w1.y = d3 * rs * ln_g[129 + c0] + ln_b[129 + c0];
        *(float2*)&xs[wv][c0] = w0;
        *(float2*)&xs[wv][128 + c0] = w1;
    }
    __syncthreads();
    int o = tid & 127, ph = tid >> 7;     // ph 0..3, handles pixels 2ph, 2ph+1
    float a0 = 0.f, a1 = 0.f;
    const float4* wp = (const float4*)WT4 + o;         // stride 128 float4s per c4
    const float4* xa = (const float4*)xs[ph * 2];
    const float4* xb4 = (const float4*)xs[ph * 2 + 1];
#pragma unroll 8
    for (int c4 = 0; c4 < 64; c4++) {
        float4 w = wp[(size_t)c4 * 128];
        float4 p0 = xa[c4], p1 = xb4[c4];
        a0 += w.x * p0.x + w.y * p0.y + w.z * p0.z + w.w * p0.w;
        a1 += w.x * p1.x + w.y * p1.y + w.z * p1.z + w.w * p1.w;
    }
#pragma unroll
    for (int k = 0; k < 2; k++) {
        int pix = blk * 8 + ph * 2 + k;
        int b = pix / HW, p = pix - b * HW;
        float a = k ? a1 : a0;
        if (o < 64) {
            q_pix[(((size_t)b * HW) + p) * 64 + o] = a;
        } else {
            int t = o - 64, g = t >> 5, c32 = t & 31;
            k_nhwc[(((size_t)(b * 2 + g) * HW) + p) * 32 + c32] = __float2half(a);
        }
    }
}

// ---------------- K3: t = GELU(LN(dw3x3(resize(q)))). Thread per (bg, pixel, ch).
// Center tap (dy=0,dx=0) IS the resized q at this pixel -> store it to qr for k5.
__global__ __launch_bounds__(256) void k3_t(const float* __restrict__ q_pix,
                                            const float* __restrict__ dwT,
                                            const float* __restrict__ og,
                                            const float* __restrict__ ob,
                                            __half* __restrict__ tbuf_h,
                                            float* __restrict__ qr) {
    int gid = blockIdx.x * 256 + threadIdx.x;   // 4*9216*32
    int c = gid & 31;
    int p2 = gid >> 5;                          // bg*9216 + p
    int bg = p2 / N1, p = p2 - bg * N1;
    int b = bg >> 1, g = bg & 1;
    int oy = p / OW, ox = p - oy * OW;
    const float* qb = q_pix + ((size_t)b * HW) * 64 + g * 32 + c;
    float acc = 0.f;
    float qcen = 0.f;
#pragma unroll
    for (int dy = -1; dy <= 1; dy++) {
        int yy = oy + dy;
        if ((unsigned)yy >= (unsigned)OH) continue;
        float ysf = yy * RESZ;
        int y0 = min((int)ysf, 46);
        float wy = ysf - (float)y0;
#pragma unroll
        for (int dx = -1; dx <= 1; dx++) {
            int xx = ox + dx;
            if ((unsigned)xx >= (unsigned)OW) continue;
            float xsf = xx * RESZ;
            int x0 = min((int)xsf, 46);
            float wx = xsf - (float)x0;
            int i00 = (y0 * 48 + x0) * 64;
            float q00 = qb[i00], q01 = qb[i00 + 64];
            float q10 = qb[i00 + 48 * 64], q11 = qb[i00 + 49 * 64];
            float qv = (q00 * (1.f - wy) + q10 * wy) * (1.f - wx)
                     + (q01 * (1.f - wy) + q11 * wy) * wx;
            acc += qv * dwT[((dy + 1) * 3 + dx + 1) * 32 + c];
            if (dy == 0 && dx == 0) qcen = qv;
        }
    }
    float s = acc;
#pragma unroll
    for (int off = 1; off < 32; off <<= 1) s += __shfl_xor(s, off);
    float mu = s * (1.f / 32.f);
    float d = acc - mu;
    float v = d * d;
#pragma unroll
    for (int off = 1; off < 32; off <<= 1) v += __shfl_xor(v, off);
    float rsv = rsqrtf(v * (1.f / 32.f) + 1e-5f);
    float t = d * rsv * og[c] + ob[c];
    float ge = 0.5f * t * (1.f + erff(t * 0.70710678118654752f));
    tbuf_h[(size_t)p2 * 32 + c] = __float2half(ge);
    qr[((size_t)b * N1 + p) * 64 + g * 32 + c] = qcen;
}

// ---------------- K4: conv 3x3 32->18 + bias.
__global__ __launch_bounds__(512) void k4_pred(const __half* __restrict__ tbuf_h,
                                               const float* __restrict__ wg2,
                                               const float* __restrict__ bsg2,
                                               float* __restrict__ pred) {
    int blk = blockIdx.x;
    int bg = blk / 144, tile = blk - bg * 144;
    int ty0 = (tile / 12) * 8, tx0 = (tile % 12) * 8;
    int tid = threadIdx.x;
    __shared__ float ts[100 * 33];   // [halo point][ic], pitch 33

    const __half* tb = tbuf_h + (size_t)bg * N1 * 32;
    for (int item = tid; item < 400; item += 512) {
        int pt = item >> 2, qg = item & 3;       // 8 channels per item
        int hy = ty0 + pt / 10 - 1;
        int hx = tx0 + pt % 10 - 1;
        float4 raw = make_float4(0.f, 0.f, 0.f, 0.f);
        if ((unsigned)hy < (unsigned)OH && (unsigned)hx < (unsigned)OW)
            raw = *(const float4*)(tb + ((size_t)(hy * OW + hx)) * 32 + qg * 8);
        const __half2* h2 = (const __half2*)&raw;
        int base = pt * 33 + qg * 8;
#pragma unroll
        for (int i = 0; i < 4; i++) {
            float2 f = __half22float2(h2[i]);
            ts[base + i * 2] = f.x;
            ts[base + i * 2 + 1] = f.y;
        }
    }
    __syncthreads();

    int w = __builtin_amdgcn_readfirstlane(tid >> 6);
    int lane = tid & 63;
    int y = lane >> 3, x = lane & 7;
    int ocb = ocb8(w), cnt = cnt8(w);
    float acc[3];
#pragma unroll
    for (int j = 0; j < 3; j++) acc[j] = bsg2[w * 3 + j];
    const float* tsb = &ts[(y * 10 + x) * 33];
    const float* wgp = wg2 + (size_t)w * 864;
    const int kof[9] = {0, 33, 66, 330, 363, 396, 660, 693, 726};
    for (int ic = 0; ic < 32; ic++) {
#pragma unroll
        for (int k = 0; k < 9; k++) {
            float tv = tsb[kof[k] + ic];
            const float* wr = wgp + (ic * 9 + k) * 3;
#pragma unroll
            for (int j = 0; j < 3; j++) acc[j] += tv * wr[j];
        }
    }
    int p = (ty0 + y) * OW + tx0 + x;
    float* pp = pred + ((size_t)bg * N1 + p) * 18 + ocb;
#pragma unroll
    for (int j = 0; j < 3; j++)
        if (j < cnt) pp[j] = acc[j];
}

// helper: weighted hfma2 accumulate of 4 corner rows into 4 half2 accumulators
#define VFMA(ACC, W, P, R0, R1, R2, R3) do {                                  \
        __half2 f0 = __float2half2_rn((W).x * (P));                           \
        __half2 f1 = __float2half2_rn((W).y * (P));                           \
        __half2 f2 = __float2half2_rn((W).z * (P));                           \
        __half2 f3 = __float2half2_rn((W).w * (P));                           \
        const __half2* H0 = (const __half2*)&(R0);                            \
        const __half2* H1 = (const __half2*)&(R1);                            \
        const __half2* H2 = (const __half2*)&(R2);                            \
        const __half2* H3 = (const __half2*)&(R3);                            \
        _Pragma("unroll")                                                     \
        for (int q = 0; q < 4; q++) {                                         \
            ACC[q] = __hfma2(f0, H0[q], ACC[q]);                              \
            ACC[q] = __hfma2(f1, H1[q], ACC[q]);                              \
            ACC[q] = __hfma2(f2, H2[q], ACC[q]);                              \
            ACC[q] = __hfma2(f3, H3[q], ACC[q]);                              \
        }                                                                     \
    } while (0)

#define VLOADA(CO) do {                                                       \
        A0 = *(const float4*)(vb + (size_t)(CO).x * 128);                     \
        A1 = *(const float4*)(vb + (size_t)(CO).y * 128);                     \
        A2 = *(const float4*)(vb + (size_t)(CO).z * 128);                     \
        A3 = *(const float4*)(vb + (size_t)(CO).w * 128);                     \
    } while (0)

#define VLOADB(CO) do {                                                       \
        B0 = *(const float4*)(vb + (size_t)(CO).x * 128);                     \
        B1 = *(const float4*)(vb + (size_t)(CO).y * 128);                     \
        B2 = *(const float4*)(vb + (size_t)(CO).z * 128);                     \
        B3 = *(const float4*)(vb + (size_t)(CO).w * 128);                     \
    } while (0)

// ---------------- K5: deformable attention. 1 wave = 2 consecutive pixels (same row);
// block = 8 pixels (4 waves). Lane remap: c2 = lane&15, jg = lane>>4.
// Score/softmax/setup identical to round-3. Value phase: 2-buffer software
// pipeline — first 8 V loads issued BEFORE the softmax; consumed buffer is
// refilled with the iteration+2 tap so >=4 float4 loads stay in flight.
__global__ __launch_bounds__(256) void k5_attn(const float* __restrict__ pred,
                                               const float* __restrict__ qr,
                                               const __half* __restrict__ k_nhwc,
                                               const __half* __restrict__ v_nhwc,
                                               const float* __restrict__ rpb,
                                               float* __restrict__ out) {
    int tid = threadIdx.x;
    int wv = __builtin_amdgcn_readfirstlane(tid >> 6);
    int lane = tid & 63;
    int gp = blockIdx.x * 8;               // block-base pixel (same bg, same row)
    int bg = gp / N1, p0 = gp % N1;
    int b = bg >> 1, g = bg & 1;
    int pw = p0 + wv * 2;                  // wave-base pixel
    int oy = pw / OW, ox0 = pw % OW;

    __shared__ float4 wts[4][2][9];        // [wave][px][tap] corner weights
    __shared__ int4   cof[4][2][9];        // [wave][px][tap] corner pixel offsets
    __shared__ float  outb[4][2][128];     // [wave][px][ch]

    // --- tap setup: lanes 0..17 -> (px, j)   (round-0 proven form)
    if (lane < 18) {
        int px = lane / 9, j = lane % 9;
        int p = pw + px;
        int ky = j / 3, kx = j % 3;
        const float* pp = pred + ((size_t)bg * N1 + p) * 18;
        float pr0 = pp[j * 2];
        float pr1 = pp[j * 2 + 1];
        float th0 = 1.f - 2.f * __builtin_amdgcn_rcpf(__expf(2.f * pr0) + 1.f);
        float th1 = 1.f - 2.f * __builtin_amdgcn_rcpf(__expf(2.f * pr1) + 1.f);
        float py  = th0 * 11.0f + (float)(ky - 1) + (float)oy;
        float pxc = th1 * 11.0f + (float)(kx - 1) + (float)(ox0 + px);
        float iy = py * RESZ, ix = pxc * RESZ;
        float y0f = floorf(iy), x0f = floorf(ix);
        float wy = iy - y0f, wx = ix - x0f;
        int y0 = (int)y0f, x0 = (int)x0f;
        bool vy0 = (unsigned)y0 < 48u, vy1 = (unsigned)(y0 + 1) < 48u;
        bool vx0 = (unsigned)x0 < 48u, vx1 = (unsigned)(x0 + 1) < 48u;
        int y0c = min(max(y0, 0), 47), y1c = min(max(y0 + 1, 0), 47);
        int x0c = min(max(x0, 0), 47), x1c = min(max(x0 + 1, 0), 47);
        float4 w;
        w.x = (vy0 && vx0) ? (1.f - wy) * (1.f - wx) : 0.f;
        w.y = (vy0 && vx1) ? (1.f - wy) * wx : 0.f;
        w.z = (vy1 && vx0) ? wy * (1.f - wx) : 0.f;
        w.w = (vy1 && vx1) ? wy * wx : 0.f;
        wts[wv][px][j] = w;
        cof[wv][px][j] = make_int4(y0c * 48 + x0c, y0c * 48 + x1c,
                                   y1c * 48 + x0c, y1c * 48 + x1c);
    }
    __syncthreads();

    int c2 = lane & 15, jg = lane >> 4;    // channel pair 0..15, tap group 0..3
    const __half* kb = k_nhwc + (size_t)bg * HW * 32 + 2 * c2;
    const float* rb = rpb + (size_t)g * 288;
    const __half* vb = v_nhwc + (size_t)bg * HW * 128 + c2 * 8;

    // rpb pairs for this lane's taps (j = jj*4 + jg)
    float2 rv[3];
#pragma unroll
    for (int jj = 0; jj < 3; jj++) {
        int j = jj * 4 + jg;
        rv[jj] = (j < 9) ? *(const float2*)(rb + j * 32 + 2 * c2) : make_float2(0.f, 0.f);
    }

    // qv pairs for both px from materialized resized q
    const float* qrb = qr + ((size_t)b * N1 + pw) * 64 + g * 32 + 2 * c2;
    float2 qv[2];
    {
        float2 t0 = *(const float2*)qrb;
        float2 t1 = *(const float2*)(qrb + 64);
        qv[0] = make_float2(t0.x * SCALE_ATTN, t0.y * SCALE_ATTN);
        qv[1] = make_float2(t1.x * SCALE_ATTN, t1.y * SCALE_ATTN);
    }

    // --- scores: 2 px x 3 jj, half2 K loads, reduce over 16 c2 lanes
    float s[2][3];
#pragma unroll
    for (int px = 0; px < 2; px++) {
#pragma unroll
        for (int jj = 0; jj < 3; jj++) {
            int j = jj * 4 + jg;
            float partial = 0.f;
            if (j < 9) {
                float4 w = wts[wv][px][j];
                int4 co = cof[wv][px][j];
                float2 k0 = __half22float2(*(const __half2*)(kb + (size_t)co.x * 32));
                float2 k1 = __half22float2(*(const __half2*)(kb + (size_t)co.y * 32));
                float2 k2 = __half22float2(*(const __half2*)(kb + (size_t)co.z * 32));
                float2 k3 = __half22float2(*(const __half2*)(kb + (size_t)co.w * 32));
                float kvx = w.x * k0.x + w.y * k1.x + w.z * k2.x + w.w * k3.x;
                float kvy = w.x * k0.y + w.y * k1.y + w.z * k2.y + w.w * k3.y;
                partial = qv[px].x * (kvx + rv[jj].x) + qv[px].y * (kvy + rv[jj].y);
            }
#pragma unroll
            for (int off = 1; off < 16; off <<= 1) partial += __shfl_xor(partial, off);
            s[px][jj] = (j < 9) ? partial : -1e30f;
        }
    }

    // --- issue first two value-iterations' V loads BEFORE softmax.
    // Iteration order it=0..5: (px=it/3, jj=it%3), tap j = jj*4+jg (jj<2 always
    // valid; jj==2 valid only for jg==0, index clamped to tap 8, weight zeroed).
    float4 A0, A1, A2, A3, B0, B1, B2, B3;
    {
        int4 ca = cof[wv][0][jg];          // it0
        int4 cb = cof[wv][0][4 + jg];      // it1
        VLOADA(ca);
        VLOADB(cb);
    }

    // --- softmax per px; reduce across the 4 tap groups (xor16, xor32)
    float pj[2][3];
#pragma unroll
    for (int px = 0; px < 2; px++) {
        float m = fmaxf(fmaxf(s[px][0], s[px][1]), s[px][2]);
        m = fmaxf(m, __shfl_xor(m, 16));
        m = fmaxf(m, __shfl_xor(m, 32));
        float e0 = __expf(s[px][0] - m);
        float e1 = __expf(s[px][1] - m);
        float e2 = __expf(s[px][2] - m);
        float sum = e0 + e1 + e2;
        sum += __shfl_xor(sum, 16);
        sum += __shfl_xor(sum, 32);
        float inv = __builtin_amdgcn_rcpf(sum);
        pj[px][0] = e0 * inv; pj[px][1] = e1 * inv; pj[px][2] = e2 * inv;
    }
    float p2a = (jg == 0) ? pj[0][2] : 0.f;   // it2 weight (tap 8, px0)
    float p2b = (jg == 0) ? pj[1][2] : 0.f;   // it5 weight (tap 8, px1)

    // --- value phase: 6 uniform iterations, 2-buffer pipeline
    __half2 acc0[4], acc1[4];
#pragma unroll
    for (int q = 0; q < 4; q++) {
        acc0[q] = __float2half2_rn(0.f);
        acc1[q] = __float2half2_rn(0.f);
    }
    { // it0: consume A (px0, tap jg); refill A <- it2 (px0, tap 8)
        float4 w = wts[wv][0][jg];
        VFMA(acc0, w, pj[0][0], A0, A1, A2, A3);
        int4 cn = cof[wv][0][8];
        VLOADA(cn);
    }
    { // it1: consume B (px0, tap 4+jg); refill B <- it3 (px1, tap jg)
        float4 w = wts[wv][0][4 + jg];
        VFMA(acc0, w, pj[0][1], B0, B1, B2, B3);
        int4 cn = cof[wv][1][jg];
        VLOADB(cn);
    }
    { // it2: consume A (px0, tap 8, weight p2a); refill A <- it4 (px1, tap 4+jg)
        float4 w = wts[wv][0][8];
        VFMA(acc0, w, p2a, A0, A1, A2, A3);
        int4 cn = cof[wv][1][4 + jg];
        VLOADA(cn);
    }
    { // it3: consume B (px1, tap jg); refill B <- it5 (px1, tap 8)
        float4 w = wts[wv][1][jg];
        VFMA(acc1, w, pj[1][0], B0, B1, B2, B3);
        int4 cn = cof[wv][1][8];
        VLOADB(cn);
    }
    { // it4: consume A (px1, tap 4+jg)
        float4 w = wts[wv][1][4 + jg];
        VFMA(acc1, w, pj[1][1], A0, A1, A2, A3);
    }
    { // it5: consume B (px1, tap 8, weight p2b)
        float4 w = wts[wv][1][8];
        VFMA(acc1, w, p2b, B0, B1, B2, B3);
    }

    // --- output: cvt to float, reduce across tap groups in float, write LDS
#pragma unroll
    for (int px = 0; px < 2; px++) {
        float f[8];
#pragma unroll
        for (int q = 0; q < 4; q++) {
            float2 t = __half22float2(px == 0 ? acc0[q] : acc1[q]);
            f[2 * q] = t.x; f[2 * q + 1] = t.y;
        }
#pragma unroll
        for (int i = 0; i < 8; i++) {
            f[i] += __shfl_xor(f[i], 16);
            f[i] += __shfl_xor(f[i], 32);
        }
        if (lane < 16) {
            *(float4*)&outb[wv][px][c2 * 8]     = make_float4(f[0], f[1], f[2], f[3]);
            *(float4*)&outb[wv][px][c2 * 8 + 4] = make_float4(f[4], f[5], f[6], f[7]);
        }
    }
    __syncthreads();

    // final write: thread t: ch = t&127, qh = t>>7 -> float4 covering px qh*4..qh*4+3
    {
        int ch = tid & 127, qh = tid >> 7;
        float* op = out + ((size_t)b * NC + g * 128 + ch) * N1 + p0 + qh * 4;
        float4 v4 = make_float4(outb[qh * 2][0][ch], outb[qh * 2][1][ch],
                                outb[qh * 2 + 1][0][ch], outb[qh * 2 + 1][1][ch]);
        *(float4*)op = v4;
    }
}

extern "C" void kernel_launch(void* const* d_in, const int* in_sizes, int n_in,
                              void* d_out, int out_size, void* d_ws, size_t ws_size,
                              hipStream_t stream) {
    const float* x      = (const float*)d_in[0];
    const float* ln_g   = (const float*)d_in[1];
    const float* ln_b   = (const float*)d_in[2];
    const float* Wq     = (const float*)d_in[3];
    const float* Wk     = (const float*)d_in[4];
    const float* dw_w   = (const float*)d_in[5];
    const float* off_g  = (const float*)d_in[6];
    const float* off_bt = (const float*)d_in[7];
    const float* off_w  = (const float*)d_in[8];
    const float* off_b  = (const float*)d_in[9];
    const float* rpb    = (const float*)d_in[10];
    float* out = (float*)d_out;

    // Workspace layout. fp32 region then fp16 region then qr. ~14 MB. NO aliasing.
    float* ws = (float*)d_ws;
    float* WT4    = ws;                       // 32768   [64][128][4]
    float* q_pix  = WT4 + 32768;              // 294912  [2][2304][64]
    float* pred   = q_pix + 294912;           // 663552  [4][9216][18]
    float* dwT    = pred + 663552;            // 288     [9][32]
    float* wg2    = dwT + 288;                // 6912    [8][288][3]
    float* bsg2   = wg2 + 6912;               // 24      [8][3]
    __half* v_nhwc = (__half*)(bsg2 + 24);    // 1179648 h [4][2304][128]
    __half* k_nhwc = v_nhwc + 1179648;        // 294912 h  [4][2304][32]
    __half* tbuf_h = k_nhwc + 294912;         // 1179648 h [4][9216][32]
    float* qr      = (float*)(tbuf_h + 1179648); // 1179648 f [2][9216][64]

    kA_prep<<<1309, 256, 0, stream>>>(x, Wq, Wk, off_w, dw_w, off_b,
                                      v_nhwc, WT4, dwT, wg2, bsg2);
    k1_ln_qk<<<576, 512, 0, stream>>>(v_nhwc, ln_g, ln_b, WT4, q_pix, k_nhwc);
    k3_t<<<4608, 256, 0, stream>>>(q_pix, dwT, off_g, off_bt, tbuf_h, qr);
    k4_pred<<<576, 512, 0, stream>>>(tbuf_h, wg2, bsg2, pred);
    k5_attn<<<4608, 256, 0, stream>>>(pred, qr, k_nhwc, v_nhwc, rpb, out);
}

// Round 6
// 157.785 us; speedup vs baseline: 1.0142x; 1.0133x over previous
//
#include <hip/hip_runtime.h>
#include <hip/hip_fp16.h>
#include <cstdint>
#include <cmath>

// Problem constants
#define NB 2
#define NC 256
#define HW 2304          // 48*48
#define HID 64
#define OH 96
#define OW 96
#define N1 9216          // 96*96
#define SCALE_ATTN 0.17677669529663689f   // 32^-0.5
#define RESZ ((float)(47.0/95.0))

// oc-group split for k4: 8 waves, counts {3,3,2,2,2,2,2,2}
__device__ __host__ inline int ocb8(int w) { return w < 2 ? 3 * w : 6 + 2 * (w - 2); }
__device__ __host__ inline int cnt8(int w) { return w < 2 ? 3 : 2; }

// ---------------- KA: fused prep.
__global__ void kA_prep(const float* __restrict__ x, const float* __restrict__ Wq,
                        const float* __restrict__ Wk, const float* __restrict__ off_w,
                        const float* __restrict__ dw_w, const float* __restrict__ off_b,
                        __half* __restrict__ v_nhwc, float* __restrict__ WT4,
                        float* __restrict__ dwT, float* __restrict__ wg2,
                        float* __restrict__ bsg2) {
    int blk = blockIdx.x;
    if (blk < 1152) {
        int pt = blk % 72;
        int t2 = blk / 72;
        int ct = t2 & 3;
        int bg = t2 >> 2;
        int b = bg >> 1, g = bg & 1;
        __shared__ float tile[32][33];
        int tx = threadIdx.x & 31, row = threadIdx.x >> 5;   // row 0..7
#pragma unroll
        for (int r = 0; r < 4; r++) {
            int c = ct * 32 + row + r * 8;
            tile[row + r * 8][tx] = x[((size_t)(b * 256 + g * 128 + c)) * HW + pt * 32 + tx];
        }
        __syncthreads();
#pragma unroll
        for (int r = 0; r < 4; r++) {
            int p = pt * 32 + row + r * 8;
            v_nhwc[((size_t)bg * HW + p) * 128 + ct * 32 + tx] =
                __float2half(tile[tx][row + r * 8]);
        }
    } else {
        int idx = (blk - 1152) * 256 + threadIdx.x;
        if (idx < 32768) {
            int c = idx >> 7, t = idx & 127;
            float v = (t < 64) ? Wq[t * 256 + c] : Wk[(t - 64) * 256 + c];
            WT4[(((size_t)(c >> 2) * 128) + t) * 4 + (c & 3)] = v;
        } else if (idx < 32768 + 288) {
            int i = idx - 32768;
            int wi = i >> 5, c = i & 31;
            dwT[i] = dw_w[c * 9 + wi];
        } else if (idx < 32768 + 288 + 8 * 288 * 3) {
            int i = idx - (32768 + 288);
            int w = i / 864, r = i - w * 864;
            int kk = r / 3, j = r - kk * 3;
            wg2[i] = (j < cnt8(w)) ? off_w[(ocb8(w) + j) * 288 + kk] : 0.f;
        } else if (idx < 32768 + 288 + 8 * 288 * 3 + 24) {
            int i = idx - (32768 + 288 + 8 * 288 * 3);
            int w = i / 3, j = i - w * 3;
            bsg2[i] = (j < cnt8(w)) ? off_b[ocb8(w) + j] : 0.f;
        }
    }
}

// ---------------- K1: channel LN over 256 + Q/K projection.
// NEW dot phase: ph (tid>>7) partitions the c4 (K) dimension, not pixels.
// WT4 is read exactly ONCE per block (128KB vs 512KB before); each thread
// computes partial dots for all 8 pixels; 4 partials combined via LDS.
__global__ __launch_bounds__(512) void k1_ln_qk(const __half* __restrict__ v_nhwc,
                         const float* __restrict__ ln_g, const float* __restrict__ ln_b,
                         const float* __restrict__ WT4,
                         float* __restrict__ q_pix, __half* __restrict__ k_nhwc) {
    int blk = blockIdx.x;            // 0..575
    int tid = threadIdx.x;
    int wv = tid >> 6, lane = tid & 63;
    __shared__ float xs[8][256];
    __shared__ float pr[4][8][128];  // [ph][px][o] partial sums (16KB)
    {
        int pix = blk * 8 + wv;
        int b = pix / HW, p = pix - b * HW;
        int c0 = lane * 2;
        __half2 h0 = *(const __half2*)(v_nhwc + (((size_t)(b * 2 + 0) * HW) + p) * 128 + c0);
        __half2 h1 = *(const __half2*)(v_nhwc + (((size_t)(b * 2 + 1) * HW) + p) * 128 + c0);
        float2 u0 = __half22float2(h0);
        float2 u1 = __half22float2(h1);
        float s = u0.x + u0.y + u1.x + u1.y;
#pragma unroll
        for (int off = 1; off < 64; off <<= 1) s += __shfl_xor(s, off);
        float mu = s * (1.f / 256.f);
        float d0 = u0.x - mu, d1 = u0.y - mu, d2 = u1.x - mu, d3 = u1.y - mu;
        float q = d0 * d0 + d1 * d1 + d2 * d2 + d3 * d3;
#pragma unroll
        for (int off = 1; off < 64; off <<= 1) q += __shfl_xor(q, off);
        float rs = rsqrtf(q * (1.f / 256.f) + 1e-5f);
        float2 w0, w1;
        w0.x = d0 * rs * ln_g[c0] + ln_b[c0];
        w0.y = d1 * rs * ln_g[c0 + 1] + ln_b[c0 + 1];
        w1.x = d2 * rs * ln_g[128 + c0] + ln_b[128 + c0];
        w1.y = d3 * rs * ln_g[129 + c0] + ln_b[129 + c0];
        *(float2*)&xs[wv][c0] = w0;
        *(float2*)&xs[wv][128 + c0] = w1;
    }
    __syncthreads();
    int o = tid & 127, ph = tid >> 7;     // ph = c4 chunk 0..3 (16 c4 each)
    const float4* wp = (const float4*)WT4 + o;         // stride 128 float4s per c4
    float acc[8];
#pragma unroll
    for (int px = 0; px < 8; px++) acc[px] = 0.f;
    int c4base = ph * 16;
#pragma unroll 4
    for (int i = 0; i < 16; i++) {
        int c4 = c4base + i;
        float4 w = wp[(size_t)c4 * 128];
#pragma unroll
        for (int px = 0; px < 8; px++) {
            float4 p = ((const float4*)xs[px])[c4];   // wave-broadcast read
            acc[px] += w.x * p.x + w.y * p.y + w.z * p.z + w.w * p.w;
        }
    }
#pragma unroll
    for (int px = 0; px < 8; px++) pr[ph][px][o] = acc[px];
    __syncthreads();
#pragma unroll
    for (int r = 0; r < 2; r++) {
        int i = tid + r * 512;                // 1024 outputs = 8 px * 128 o
        int px = i >> 7, oo = i & 127;
        float a = pr[0][px][oo] + pr[1][px][oo] + pr[2][px][oo] + pr[3][px][oo];
        int pix = blk * 8 + px;
        int b = pix / HW, p = pix - b * HW;
        if (oo < 64) {
            q_pix[(((size_t)b * HW) + p) * 64 + oo] = a;
        } else {
            int t = oo - 64, g = t >> 5, c32 = t & 31;
            k_nhwc[(((size_t)(b * 2 + g) * HW) + p) * 32 + c32] = __float2half(a);
        }
    }
}

// ---------------- K3: t = GELU(LN(dw3x3(resize(q)))). Thread per (bg, pixel, ch).
// Center tap (dy=0,dx=0) IS the resized q at this pixel -> store it to qr for k5.
__global__ __launch_bounds__(256) void k3_t(const float* __restrict__ q_pix,
                                            const float* __restrict__ dwT,
                                            const float* __restrict__ og,
                                            const float* __restrict__ ob,
                                            __half* __restrict__ tbuf_h,
                                            float* __restrict__ qr) {
    int gid = blockIdx.x * 256 + threadIdx.x;   // 4*9216*32
    int c = gid & 31;
    int p2 = gid >> 5;                          // bg*9216 + p
    int bg = p2 / N1, p = p2 - bg * N1;
    int b = bg >> 1, g = bg & 1;
    int oy = p / OW, ox = p - oy * OW;
    const float* qb = q_pix + ((size_t)b * HW) * 64 + g * 32 + c;
    float acc = 0.f;
    float qcen = 0.f;
#pragma unroll
    for (int dy = -1; dy <= 1; dy++) {
        int yy = oy + dy;
        if ((unsigned)yy >= (unsigned)OH) continue;
        float ysf = yy * RESZ;
        int y0 = min((int)ysf, 46);
        float wy = ysf - (float)y0;
#pragma unroll
        for (int dx = -1; dx <= 1; dx++) {
            int xx = ox + dx;
            if ((unsigned)xx >= (unsigned)OW) continue;
            float xsf = xx * RESZ;
            int x0 = min((int)xsf, 46);
            float wx = xsf - (float)x0;
            int i00 = (y0 * 48 + x0) * 64;
            float q00 = qb[i00], q01 = qb[i00 + 64];
            float q10 = qb[i00 + 48 * 64], q11 = qb[i00 + 49 * 64];
            float qv = (q00 * (1.f - wy) + q10 * wy) * (1.f - wx)
                     + (q01 * (1.f - wy) + q11 * wy) * wx;
            acc += qv * dwT[((dy + 1) * 3 + dx + 1) * 32 + c];
            if (dy == 0 && dx == 0) qcen = qv;
        }
    }
    float s = acc;
#pragma unroll
    for (int off = 1; off < 32; off <<= 1) s += __shfl_xor(s, off);
    float mu = s * (1.f / 32.f);
    float d = acc - mu;
    float v = d * d;
#pragma unroll
    for (int off = 1; off < 32; off <<= 1) v += __shfl_xor(v, off);
    float rsv = rsqrtf(v * (1.f / 32.f) + 1e-5f);
    float t = d * rsv * og[c] + ob[c];
    float ge = 0.5f * t * (1.f + erff(t * 0.70710678118654752f));
    tbuf_h[(size_t)p2 * 32 + c] = __float2half(ge);
    qr[((size_t)b * N1 + p) * 64 + g * 32 + c] = qcen;
}

// ---------------- K4: conv 3x3 32->18 + bias.
__global__ __launch_bounds__(512) void k4_pred(const __half* __restrict__ tbuf_h,
                                               const float* __restrict__ wg2,
                                               const float* __restrict__ bsg2,
                                               float* __restrict__ pred) {
    int blk = blockIdx.x;
    int bg = blk / 144, tile = blk - bg * 144;
    int ty0 = (tile / 12) * 8, tx0 = (tile % 12) * 8;
    int tid = threadIdx.x;
    __shared__ float ts[100 * 33];   // [halo point][ic], pitch 33

    const __half* tb = tbuf_h + (size_t)bg * N1 * 32;
    for (int item = tid; item < 400; item += 512) {
        int pt = item >> 2, qg = item & 3;       // 8 channels per item
        int hy = ty0 + pt / 10 - 1;
        int hx = tx0 + pt % 10 - 1;
        float4 raw = make_float4(0.f, 0.f, 0.f, 0.f);
        if ((unsigned)hy < (unsigned)OH && (unsigned)hx < (unsigned)OW)
            raw = *(const float4*)(tb + ((size_t)(hy * OW + hx)) * 32 + qg * 8);
        const __half2* h2 = (const __half2*)&raw;
        int base = pt * 33 + qg * 8;
#pragma unroll
        for (int i = 0; i < 4; i++) {
            float2 f = __half22float2(h2[i]);
            ts[base + i * 2] = f.x;
            ts[base + i * 2 + 1] = f.y;
        }
    }
    __syncthreads();

    int w = __builtin_amdgcn_readfirstlane(tid >> 6);
    int lane = tid & 63;
    int y = lane >> 3, x = lane & 7;
    int ocb = ocb8(w), cnt = cnt8(w);
    float acc[3];
#pragma unroll
    for (int j = 0; j < 3; j++) acc[j] = bsg2[w * 3 + j];
    const float* tsb = &ts[(y * 10 + x) * 33];
    const float* wgp = wg2 + (size_t)w * 864;
    const int kof[9] = {0, 33, 66, 330, 363, 396, 660, 693, 726};
    for (int ic = 0; ic < 32; ic++) {
#pragma unroll
        for (int k = 0; k < 9; k++) {
            float tv = tsb[kof[k] + ic];
            const float* wr = wgp + (ic * 9 + k) * 3;
#pragma unroll
            for (int j = 0; j < 3; j++) acc[j] += tv * wr[j];
        }
    }
    int p = (ty0 + y) * OW + tx0 + x;
    float* pp = pred + ((size_t)bg * N1 + p) * 18 + ocb;
#pragma unroll
    for (int j = 0; j < 3; j++)
        if (j < cnt) pp[j] = acc[j];
}

// ---------------- K5: deformable attention (round-3 proven form, VGPR~44,
// 8 waves/SIMD). 1 wave = 2 consecutive pixels; c2 = lane&15, jg = lane>>4.
__global__ __launch_bounds__(256) void k5_attn(const float* __restrict__ pred,
                                               const float* __restrict__ qr,
                                               const __half* __restrict__ k_nhwc,
                                               const __half* __restrict__ v_nhwc,
                                               const float* __restrict__ rpb,
                                               float* __restrict__ out) {
    int tid = threadIdx.x;
    int wv = __builtin_amdgcn_readfirstlane(tid >> 6);
    int lane = tid & 63;
    int gp = blockIdx.x * 8;               // block-base pixel (same bg, same row)
    int bg = gp / N1, p0 = gp % N1;
    int b = bg >> 1, g = bg & 1;
    int pw = p0 + wv * 2;                  // wave-base pixel
    int oy = pw / OW, ox0 = pw % OW;

    __shared__ float4 wts[4][2][9];        // [wave][px][tap] corner weights
    __shared__ int4   cof[4][2][9];        // [wave][px][tap] corner pixel offsets
    __shared__ float  outb[4][2][128];     // [wave][px][ch]

    // --- tap setup: lanes 0..17 -> (px, j)
    if (lane < 18) {
        int px = lane / 9, j = lane % 9;
        int p = pw + px;
        int ky = j / 3, kx = j % 3;
        const float* pp = pred + ((size_t)bg * N1 + p) * 18;
        float pr0 = pp[j * 2];
        float pr1 = pp[j * 2 + 1];
        float th0 = 1.f - 2.f * __builtin_amdgcn_rcpf(__expf(2.f * pr0) + 1.f);
        float th1 = 1.f - 2.f * __builtin_amdgcn_rcpf(__expf(2.f * pr1) + 1.f);
        float py  = th0 * 11.0f + (float)(ky - 1) + (float)oy;
        float pxc = th1 * 11.0f + (float)(kx - 1) + (float)(ox0 + px);
        float iy = py * RESZ, ix = pxc * RESZ;
        float y0f = floorf(iy), x0f = floorf(ix);
        float wy = iy - y0f, wx = ix - x0f;
        int y0 = (int)y0f, x0 = (int)x0f;
        bool vy0 = (unsigned)y0 < 48u, vy1 = (unsigned)(y0 + 1) < 48u;
        bool vx0 = (unsigned)x0 < 48u, vx1 = (unsigned)(x0 + 1) < 48u;
        int y0c = min(max(y0, 0), 47), y1c = min(max(y0 + 1, 0), 47);
        int x0c = min(max(x0, 0), 47), x1c = min(max(x0 + 1, 0), 47);
        float4 w;
        w.x = (vy0 && vx0) ? (1.f - wy) * (1.f - wx) : 0.f;
        w.y = (vy0 && vx1) ? (1.f - wy) * wx : 0.f;
        w.z = (vy1 && vx0) ? wy * (1.f - wx) : 0.f;
        w.w = (vy1 && vx1) ? wy * wx : 0.f;
        wts[wv][px][j] = w;
        cof[wv][px][j] = make_int4(y0c * 48 + x0c, y0c * 48 + x1c,
                                   y1c * 48 + x0c, y1c * 48 + x1c);
    }
    __syncthreads();

    int c2 = lane & 15, jg = lane >> 4;    // channel pair 0..15, tap group 0..3
    const __half* kb = k_nhwc + (size_t)bg * HW * 32 + 2 * c2;
    const float* rb = rpb + (size_t)g * 288;
    const __half* vb = v_nhwc + (size_t)bg * HW * 128 + c2 * 8;

    // rpb pairs for this lane's taps (j = jj*4 + jg)
    float2 rv[3];
#pragma unroll
    for (int jj = 0; jj < 3; jj++) {
        int j = jj * 4 + jg;
        rv[jj] = (j < 9) ? *(const float2*)(rb + j * 32 + 2 * c2) : make_float2(0.f, 0.f);
    }

    // qv pairs for both px from materialized resized q
    const float* qrb = qr + ((size_t)b * N1 + pw) * 64 + g * 32 + 2 * c2;
    float2 qv[2];
    {
        float2 t0 = *(const float2*)qrb;
        float2 t1 = *(const float2*)(qrb + 64);
        qv[0] = make_float2(t0.x * SCALE_ATTN, t0.y * SCALE_ATTN);
        qv[1] = make_float2(t1.x * SCALE_ATTN, t1.y * SCALE_ATTN);
    }

    // --- scores: 2 px x 3 jj, half2 K loads, reduce over 16 c2 lanes
    float s[2][3];
#pragma unroll
    for (int px = 0; px < 2; px++) {
#pragma unroll
        for (int jj = 0; jj < 3; jj++) {
            int j = jj * 4 + jg;
            float partial = 0.f;
            if (j < 9) {
                float4 w = wts[wv][px][j];
                int4 co = cof[wv][px][j];
                float2 k0 = __half22float2(*(const __half2*)(kb + (size_t)co.x * 32));
                float2 k1 = __half22float2(*(const __half2*)(kb + (size_t)co.y * 32));
                float2 k2 = __half22float2(*(const __half2*)(kb + (size_t)co.z * 32));
                float2 k3 = __half22float2(*(const __half2*)(kb + (size_t)co.w * 32));
                float kvx = w.x * k0.x + w.y * k1.x + w.z * k2.x + w.w * k3.x;
                float kvy = w.x * k0.y + w.y * k1.y + w.z * k2.y + w.w * k3.y;
                partial = qv[px].x * (kvx + rv[jj].x) + qv[px].y * (kvy + rv[jj].y);
            }
#pragma unroll
            for (int off = 1; off < 16; off <<= 1) partial += __shfl_xor(partial, off);
            s[px][jj] = (j < 9) ? partial : -1e30f;
        }
    }

    // --- softmax per px; reduce across the 4 tap groups (xor16, xor32)
    float pj[2][3];
#pragma unroll
    for (int px = 0; px < 2; px++) {
        float m = fmaxf(fmaxf(s[px][0], s[px][1]), s[px][2]);
        m = fmaxf(m, __shfl_xor(m, 16));
        m = fmaxf(m, __shfl_xor(m, 32));
        float e0 = __expf(s[px][0] - m);
        float e1 = __expf(s[px][1] - m);
        float e2 = __expf(s[px][2] - m);
        float sum = e0 + e1 + e2;
        sum += __shfl_xor(sum, 16);
        sum += __shfl_xor(sum, 32);
        float inv = __builtin_amdgcn_rcpf(sum);
        pj[px][0] = e0 * inv; pj[px][1] = e1 * inv; pj[px][2] = e2 * inv;
    }

    // --- value phase: 16B V loads (8 channels/lane), packed __hfma2 accumulation
    __half2 acc[2][4];
#pragma unroll
    for (int px = 0; px < 2; px++)
#pragma unroll
        for (int q = 0; q < 4; q++) acc[px][q] = __float2half2_rn(0.f);

#pragma unroll
    for (int px = 0; px < 2; px++) {
#pragma unroll
        for (int jj = 0; jj < 3; jj++) {
            int j = jj * 4 + jg;
            if (j < 9) {
                float p = pj[px][jj];
                float4 w = wts[wv][px][j];
                int4 co = cof[wv][px][j];
                float4 r0 = *(const float4*)(vb + (size_t)co.x * 128);
                float4 r1 = *(const float4*)(vb + (size_t)co.y * 128);
                float4 r2 = *(const float4*)(vb + (size_t)co.z * 128);
                float4 r3 = *(const float4*)(vb + (size_t)co.w * 128);
                const __half2* A0 = (const __half2*)&r0;
                const __half2* A1 = (const __half2*)&r1;
                const __half2* A2 = (const __half2*)&r2;
                const __half2* A3 = (const __half2*)&r3;
                __half2 f0 = __float2half2_rn(w.x * p);
                __half2 f1 = __float2half2_rn(w.y * p);
                __half2 f2 = __float2half2_rn(w.z * p);
                __half2 f3 = __float2half2_rn(w.w * p);
#pragma unroll
                for (int q = 0; q < 4; q++) {
                    acc[px][q] = __hfma2(f0, A0[q], acc[px][q]);
                    acc[px][q] = __hfma2(f1, A1[q], acc[px][q]);
                    acc[px][q] = __hfma2(f2, A2[q], acc[px][q]);
                    acc[px][q] = __hfma2(f3, A3[q], acc[px][q]);
                }
            }
        }
    }

    // --- output: cvt to float, reduce across tap groups in float, write LDS
#pragma unroll
    for (int px = 0; px < 2; px++) {
        float f[8];
#pragma unroll
        for (int q = 0; q < 4; q++) {
            float2 t = __half22float2(acc[px][q]);
            f[2 * q] = t.x; f[2 * q + 1] = t.y;
        }
#pragma unroll
        for (int i = 0; i < 8; i++) {
            f[i] += __shfl_xor(f[i], 16);
            f[i] += __shfl_xor(f[i], 32);
        }
        if (lane < 16) {
            *(float4*)&outb[wv][px][c2 * 8]     = make_float4(f[0], f[1], f[2], f[3]);
            *(float4*)&outb[wv][px][c2 * 8 + 4] = make_float4(f[4], f[5], f[6], f[7]);
        }
    }
    __syncthreads();

    // final write: thread t: ch = t&127, qh = t>>7 -> float4 covering px qh*4..qh*4+3
    {
        int ch = tid & 127, qh = tid >> 7;
        float* op = out + ((size_t)b * NC + g * 128 + ch) * N1 + p0 + qh * 4;
        float4 v4 = make_float4(outb[qh * 2][0][ch], outb[qh * 2][1][ch],
                                outb[qh * 2 + 1][0][ch], outb[qh * 2 + 1][1][ch]);
        *(float4*)op = v4;
    }
}

extern "C" void kernel_launch(void* const* d_in, const int* in_sizes, int n_in,
                              void* d_out, int out_size, void* d_ws, size_t ws_size,
                              hipStream_t stream) {
    const float* x      = (const float*)d_in[0];
    const float* ln_g   = (const float*)d_in[1];
    const float* ln_b   = (const float*)d_in[2];
    const float* Wq     = (const float*)d_in[3];
    const float* Wk     = (const float*)d_in[4];
    const float* dw_w   = (const float*)d_in[5];
    const float* off_g  = (const float*)d_in[6];
    const float* off_bt = (const float*)d_in[7];
    const float* off_w  = (const float*)d_in[8];
    const float* off_b  = (const float*)d_in[9];
    const float* rpb    = (const float*)d_in[10];
    float* out = (float*)d_out;

    // Workspace layout. fp32 region then fp16 region then qr. ~14 MB. NO aliasing.
    float* ws = (float*)d_ws;
    float* WT4    = ws;                       // 32768   [64][128][4]
    float* q_pix  = WT4 + 32768;              // 294912  [2][2304][64]
    float* pred   = q_pix + 294912;           // 663552  [4][9216][18]
    float* dwT    = pred + 663552;            // 288     [9][32]
    float* wg2    = dwT + 288;                // 6912    [8][288][3]
    float* bsg2   = wg2 + 6912;               // 24      [8][3]
    __half* v_nhwc = (__half*)(bsg2 + 24);    // 1179648 h [4][2304][128]
    __half* k_nhwc = v_nhwc + 1179648;        // 294912 h  [4][2304][32]
    __half* tbuf_h = k_nhwc + 294912;         // 1179648 h [4][9216][32]
    float* qr      = (float*)(tbuf_h + 1179648); // 1179648 f [2][9216][64]

    kA_prep<<<1309, 256, 0, stream>>>(x, Wq, Wk, off_w, dw_w, off_b,
                                      v_nhwc, WT4, dwT, wg2, bsg2);
    k1_ln_qk<<<576, 512, 0, stream>>>(v_nhwc, ln_g, ln_b, WT4, q_pix, k_nhwc);
    k3_t<<<4608, 256, 0, stream>>>(q_pix, dwT, off_g, off_bt, tbuf_h, qr);
    k4_pred<<<576, 512, 0, stream>>>(tbuf_h, wg2, bsg2, pred);
    k5_attn<<<4608, 256, 0, stream>>>(pred, qr, k_nhwc, v_nhwc, rpb, out);
}

// Round 8
// 154.501 us; speedup vs baseline: 1.0358x; 1.0213x over previous
//
#include <hip/hip_runtime.h>
#include <hip/hip_fp16.h>
#include <cstdint>
#include <cmath>

// Problem constants
#define NB 2
#define NC 256
#define HW 2304          // 48*48
#define HID 64
#define OH 96
#define OW 96
#define N1 9216          // 96*96
#define SCALE_ATTN 0.17677669529663689f   // 32^-0.5
#define RESZ ((float)(47.0/95.0))

// oc-group split for k4 phase-3: 8 waves, counts {3,3,2,2,2,2,2,2}
__device__ __host__ inline int ocb8(int w) { return w < 2 ? 3 * w : 6 + 2 * (w - 2); }
__device__ __host__ inline int cnt8(int w) { return w < 2 ? 3 : 2; }

// ---------------- KA: fused prep.
__global__ void kA_prep(const float* __restrict__ x, const float* __restrict__ Wq,
                        const float* __restrict__ Wk, const float* __restrict__ off_w,
                        const float* __restrict__ dw_w, const float* __restrict__ off_b,
                        __half* __restrict__ v_nhwc, float* __restrict__ WT4,
                        float* __restrict__ dwT, float* __restrict__ wg2,
                        float* __restrict__ bsg2) {
    int blk = blockIdx.x;
    if (blk < 1152) {
        int pt = blk % 72;
        int t2 = blk / 72;
        int ct = t2 & 3;
        int bg = t2 >> 2;
        int b = bg >> 1, g = bg & 1;
        __shared__ float tile[32][33];
        int tx = threadIdx.x & 31, row = threadIdx.x >> 5;   // row 0..7
#pragma unroll
        for (int r = 0; r < 4; r++) {
            int c = ct * 32 + row + r * 8;
            tile[row + r * 8][tx] = x[((size_t)(b * 256 + g * 128 + c)) * HW + pt * 32 + tx];
        }
        __syncthreads();
#pragma unroll
        for (int r = 0; r < 4; r++) {
            int p = pt * 32 + row + r * 8;
            v_nhwc[((size_t)bg * HW + p) * 128 + ct * 32 + tx] =
                __float2half(tile[tx][row + r * 8]);
        }
    } else {
        int idx = (blk - 1152) * 256 + threadIdx.x;
        if (idx < 32768) {
            int c = idx >> 7, t = idx & 127;
            float v = (t < 64) ? Wq[t * 256 + c] : Wk[(t - 64) * 256 + c];
            WT4[(((size_t)(c >> 2) * 128) + t) * 4 + (c & 3)] = v;
        } else if (idx < 32768 + 288) {
            int i = idx - 32768;
            int wi = i >> 5, c = i & 31;
            dwT[i] = dw_w[c * 9 + wi];
        } else if (idx < 32768 + 288 + 8 * 288 * 3) {
            int i = idx - (32768 + 288);
            int w = i / 864, r = i - w * 864;
            int kk = r / 3, j = r - kk * 3;
            wg2[i] = (j < cnt8(w)) ? off_w[(ocb8(w) + j) * 288 + kk] : 0.f;
        } else if (idx < 32768 + 288 + 8 * 288 * 3 + 24) {
            int i = idx - (32768 + 288 + 8 * 288 * 3);
            int w = i / 3, j = i - w * 3;
            bsg2[i] = (j < cnt8(w)) ? off_b[ocb8(w) + j] : 0.f;
        }
    }
}

// ---------------- K1: channel LN over 256 + Q/K projection (r3-proven form).
__global__ __launch_bounds__(512) void k1_ln_qk(const __half* __restrict__ v_nhwc,
                         const float* __restrict__ ln_g, const float* __restrict__ ln_b,
                         const float* __restrict__ WT4,
                         float* __restrict__ q_pix, __half* __restrict__ k_nhwc) {
    int blk = blockIdx.x;            // 0..575
    int tid = threadIdx.x;
    int wv = tid >> 6, lane = tid & 63;
    __shared__ float xs[8][256];
    {
        int pix = blk * 8 + wv;
        int b = pix / HW, p = pix - b * HW;
        int c0 = lane * 2;
        __half2 h0 = *(const __half2*)(v_nhwc + (((size_t)(b * 2 + 0) * HW) + p) * 128 + c0);
        __half2 h1 = *(const __half2*)(v_nhwc + (((size_t)(b * 2 + 1) * HW) + p) * 128 + c0);
        float2 u0 = __half22float2(h0);
        float2 u1 = __half22float2(h1);
        float s = u0.x + u0.y + u1.x + u1.y;
#pragma unroll
        for (int off = 1; off < 64; off <<= 1) s += __shfl_xor(s, off);
        float mu = s * (1.f / 256.f);
        float d0 = u0.x - mu, d1 = u0.y - mu, d2 = u1.x - mu, d3 = u1.y - mu;
        float q = d0 * d0 + d1 * d1 + d2 * d2 + d3 * d3;
#pragma unroll
        for (int off = 1; off < 64; off <<= 1) q += __shfl_xor(q, off);
        float rs = rsqrtf(q * (1.f / 256.f) + 1e-5f);
        float2 w0, w1;
        w0.x = d0 * rs * ln_g[c0] + ln_b[c0];
        w0.y = d1 * rs * ln_g[c0 + 1] + ln_b[c0 + 1];
        w1.x = d2 * rs * ln_g[128 + c0] + ln_b[128 + c0];
        w1.y = d3 * rs * ln_g[129 + c0] + ln_b[129 + c0];
        *(float2*)&xs[wv][c0] = w0;
        *(float2*)&xs[wv][128 + c0] = w1;
    }
    __syncthreads();
    int o = tid & 127, ph = tid >> 7;     // ph 0..3, handles pixels 2ph, 2ph+1
    float a0 = 0.f, a1 = 0.f;
    const float4* wp = (const float4*)WT4 + o;         // stride 128 float4s per c4
    const float4* xa = (const float4*)xs[ph * 2];
    const float4* xb4 = (const float4*)xs[ph * 2 + 1];
#pragma unroll 8
    for (int c4 = 0; c4 < 64; c4++) {
        float4 w = wp[(size_t)c4 * 128];
        float4 p0 = xa[c4], p1 = xb4[c4];
        a0 += w.x * p0.x + w.y * p0.y + w.z * p0.z + w.w * p0.w;
        a1 += w.x * p1.x + w.y * p1.y + w.z * p1.z + w.w * p1.w;
    }
#pragma unroll
    for (int k = 0; k < 2; k++) {
        int pix = blk * 8 + ph * 2 + k;
        int b = pix / HW, p = pix - b * HW;
        float a = k ? a1 : a0;
        if (o < 64) {
            q_pix[(((size_t)b * HW) + p) * 64 + o] = a;
        } else {
            int t = o - 64, g = t >> 5, c32 = t & 31;
            k_nhwc[(((size_t)(b * 2 + g) * HW) + p) * 32 + c32] = __float2half(a);
        }
    }
}

// ---------------- K34: fused k3+k4. Per tile (8x8 output): compute resized-q
// on 12x12 halo into LDS (4 coalesced gathers/point), write qr for interior,
// then t = GELU(LN(dw3x3)) at 10x10 halo (fp32, in LDS), then conv 32->18.
__global__ __launch_bounds__(512) void k34_t_pred(const float* __restrict__ q_pix,
                                                  const float* __restrict__ dwT,
                                                  const float* __restrict__ og,
                                                  const float* __restrict__ ob,
                                                  const float* __restrict__ wg2,
                                                  const float* __restrict__ bsg2,
                                                  float* __restrict__ qr,
                                                  float* __restrict__ pred) {
    int blk = blockIdx.x;                 // 576 = 4 bg * 144 tiles
    int bg = blk / 144, tile = blk - bg * 144;
    int ty0 = (tile / 12) * 8, tx0 = (tile % 12) * 8;
    int tid = threadIdx.x;
    int b = bg >> 1, g = bg & 1;

    __shared__ float rq[144 * 32];        // [12x12 halo][32ch], 18KB
    __shared__ float ts[100 * 33];        // [10x10 halo][ic], pitch 33, 13.2KB

    const float* qb = q_pix + (size_t)b * HW * 64 + g * 32;

    // --- phase 1: resized q on 12x12 halo (rq row r <-> oy = ty0-2+r)
    for (int item = tid; item < 144 * 32; item += 512) {
        int pt = item >> 5, c = item & 31;
        int ry = ty0 + (pt / 12) - 2;
        int rx = tx0 + (pt % 12) - 2;
        float val = 0.f;
        if ((unsigned)ry < 96u && (unsigned)rx < 96u) {
            float ysf = ry * RESZ;
            int y0 = min((int)ysf, 46);
            float wy = ysf - (float)y0;
            float xsf = rx * RESZ;
            int x0 = min((int)xsf, 46);
            float wx = xsf - (float)x0;
            const float* q0 = qb + (y0 * 48 + x0) * 64 + c;
            float q00 = q0[0], q01 = q0[64];
            float q10 = q0[48 * 64], q11 = q0[49 * 64];
            val = (q00 * (1.f - wy) + q10 * wy) * (1.f - wx)
                + (q01 * (1.f - wy) + q11 * wy) * wx;
        }
        rq[pt * 32 + c] = val;
    }
    __syncthreads();

    // --- write qr for the interior 8x8 (each output pixel exactly once)
    for (int item = tid; item < 64 * 32; item += 512) {
        int pt = item >> 5, c = item & 31;
        int iy = pt >> 3, ix = pt & 7;
        int p = (ty0 + iy) * OW + tx0 + ix;
        int rpt = (iy + 2) * 12 + (ix + 2);
        qr[((size_t)b * N1 + p) * 64 + g * 32 + c] = rq[rpt * 32 + c];
    }

    // --- phase 2: t on 10x10 halo. 16 points/pass (32 lanes = one point's ch).
    {
        int c = tid & 31, grp = tid >> 5;          // grp 0..15
        for (int pass = 0; pass < 7; pass++) {
            int pt = pass * 16 + grp;              // 0..111
            if (pt < 100) {
                int u = pt / 10, v = pt - u * 10;  // t halo coords
                int hy = ty0 + u - 1, hx = tx0 + v - 1;
                float tval = 0.f;
                if ((unsigned)hy < 96u && (unsigned)hx < 96u) {
                    float acc = 0.f;
#pragma unroll
                    for (int dy = 0; dy < 3; dy++)
#pragma unroll
                        for (int dx = 0; dx < 3; dx++)
                            acc += rq[((u + dy) * 12 + (v + dx)) * 32 + c]
                                 * dwT[(dy * 3 + dx) * 32 + c];
                    float s = acc;
#pragma unroll
                    for (int off = 1; off < 32; off <<= 1) s += __shfl_xor(s, off);
                    float mu = s * (1.f / 32.f);
                    float d = acc - mu;
                    float vv = d * d;
#pragma unroll
                    for (int off = 1; off < 32; off <<= 1) vv += __shfl_xor(vv, off);
                    float rsv = rsqrtf(vv * (1.f / 32.f) + 1e-5f);
                    float t = d * rsv * og[c] + ob[c];
                    tval = 0.5f * t * (1.f + erff(t * 0.70710678118654752f));
                }
                ts[pt * 33 + c] = tval;
            }
        }
    }
    __syncthreads();

    // --- phase 3: conv 3x3 32->18 + bias (old k4 compute, unchanged)
    int w = __builtin_amdgcn_readfirstlane(tid >> 6);
    int lane = tid & 63;
    int y = lane >> 3, x = lane & 7;
    int ocb = ocb8(w), cnt = cnt8(w);
    float acc[3];
#pragma unroll
    for (int j = 0; j < 3; j++) acc[j] = bsg2[w * 3 + j];
    const float* tsb = &ts[(y * 10 + x) * 33];
    const float* wgp = wg2 + (size_t)w * 864;
    const int kof[9] = {0, 33, 66, 330, 363, 396, 660, 693, 726};
    for (int ic = 0; ic < 32; ic++) {
#pragma unroll
        for (int k = 0; k < 9; k++) {
            float tv = tsb[kof[k] + ic];
            const float* wr = wgp + (ic * 9 + k) * 3;
#pragma unroll
            for (int j = 0; j < 3; j++) acc[j] += tv * wr[j];
        }
    }
    int p = (ty0 + y) * OW + tx0 + x;
    float* pp = pred + ((size_t)bg * N1 + p) * 18 + ocb;
#pragma unroll
    for (int j = 0; j < 3; j++)
        if (j < cnt) pp[j] = acc[j];
}

// ---------------- K5: deformable attention (round-3 proven form, do not touch).
__global__ __launch_bounds__(256) void k5_attn(const float* __restrict__ pred,
                                               const float* __restrict__ qr,
                                               const __half* __restrict__ k_nhwc,
                                               const __half* __restrict__ v_nhwc,
                                               const float* __restrict__ rpb,
                                               float* __restrict__ out) {
    int tid = threadIdx.x;
    int wv = __builtin_amdgcn_readfirstlane(tid >> 6);
    int lane = tid & 63;
    int gp = blockIdx.x * 8;               // block-base pixel (same bg, same row)
    int bg = gp / N1, p0 = gp % N1;
    int b = bg >> 1, g = bg & 1;
    int pw = p0 + wv * 2;                  // wave-base pixel
    int oy = pw / OW, ox0 = pw % OW;

    __shared__ float4 wts[4][2][9];        // [wave][px][tap] corner weights
    __shared__ int4   cof[4][2][9];        // [wave][px][tap] corner pixel offsets
    __shared__ float  outb[4][2][128];     // [wave][px][ch]

    // --- tap setup: lanes 0..17 -> (px, j)
    if (lane < 18) {
        int px = lane / 9, j = lane % 9;
        int p = pw + px;
        int ky = j / 3, kx = j % 3;
        const float* pp = pred + ((size_t)bg * N1 + p) * 18;
        float pr0 = pp[j * 2];
        float pr1 = pp[j * 2 + 1];
        float th0 = 1.f - 2.f * __builtin_amdgcn_rcpf(__expf(2.f * pr0) + 1.f);
        float th1 = 1.f - 2.f * __builtin_amdgcn_rcpf(__expf(2.f * pr1) + 1.f);
        float py  = th0 * 11.0f + (float)(ky - 1) + (float)oy;
        float pxc = th1 * 11.0f + (float)(kx - 1) + (float)(ox0 + px);
        float iy = py * RESZ, ix = pxc * RESZ;
        float y0f = floorf(iy), x0f = floorf(ix);
        float wy = iy - y0f, wx = ix - x0f;
        int y0 = (int)y0f, x0 = (int)x0f;
        bool vy0 = (unsigned)y0 < 48u, vy1 = (unsigned)(y0 + 1) < 48u;
        bool vx0 = (unsigned)x0 < 48u, vx1 = (unsigned)(x0 + 1) < 48u;
        int y0c = min(max(y0, 0), 47), y1c = min(max(y0 + 1, 0), 47);
        int x0c = min(max(x0, 0), 47), x1c = min(max(x0 + 1, 0), 47);
        float4 w;
        w.x = (vy0 && vx0) ? (1.f - wy) * (1.f - wx) : 0.f;
        w.y = (vy0 && vx1) ? (1.f - wy) * wx : 0.f;
        w.z = (vy1 && vx0) ? wy * (1.f - wx) : 0.f;
        w.w = (vy1 && vx1) ? wy * wx : 0.f;
        wts[wv][px][j] = w;
        cof[wv][px][j] = make_int4(y0c * 48 + x0c, y0c * 48 + x1c,
                                   y1c * 48 + x0c, y1c * 48 + x1c);
    }
    __syncthreads();

    int c2 = lane & 15, jg = lane >> 4;    // channel pair 0..15, tap group 0..3
    const __half* kb = k_nhwc + (size_t)bg * HW * 32 + 2 * c2;
    const float* rb = rpb + (size_t)g * 288;
    const __half* vb = v_nhwc + (size_t)bg * HW * 128 + c2 * 8;

    // rpb pairs for this lane's taps (j = jj*4 + jg)
    float2 rv[3];
#pragma unroll
    for (int jj = 0; jj < 3; jj++) {
        int j = jj * 4 + jg;
        rv[jj] = (j < 9) ? *(const float2*)(rb + j * 32 + 2 * c2) : make_float2(0.f, 0.f);
    }

    // qv pairs for both px from materialized resized q
    const float* qrb = qr + ((size_t)b * N1 + pw) * 64 + g * 32 + 2 * c2;
    float2 qv[2];
    {
        float2 t0 = *(const float2*)qrb;
        float2 t1 = *(const float2*)(qrb + 64);
        qv[0] = make_float2(t0.x * SCALE_ATTN, t0.y * SCALE_ATTN);
        qv[1] = make_float2(t1.x * SCALE_ATTN, t1.y * SCALE_ATTN);
    }

    // --- scores: 2 px x 3 jj, half2 K loads, reduce over 16 c2 lanes
    float s[2][3];
#pragma unroll
    for (int px = 0; px < 2; px++) {
#pragma unroll
        for (int jj = 0; jj < 3; jj++) {
            int j = jj * 4 + jg;
            float partial = 0.f;
            if (j < 9) {
                float4 w = wts[wv][px][j];
                int4 co = cof[wv][px][j];
                float2 k0 = __half22float2(*(const __half2*)(kb + (size_t)co.x * 32));
                float2 k1 = __half22float2(*(const __half2*)(kb + (size_t)co.y * 32));
                float2 k2 = __half22float2(*(const __half2*)(kb + (size_t)co.z * 32));
                float2 k3 = __half22float2(*(const __half2*)(kb + (size_t)co.w * 32));
                float kvx = w.x * k0.x + w.y * k1.x + w.z * k2.x + w.w * k3.x;
                float kvy = w.x * k0.y + w.y * k1.y + w.z * k2.y + w.w * k3.y;
                partial = qv[px].x * (kvx + rv[jj].x) + qv[px].y * (kvy + rv[jj].y);
            }
#pragma unroll
            for (int off = 1; off < 16; off <<= 1) partial += __shfl_xor(partial, off);
            s[px][jj] = (j < 9) ? partial : -1e30f;
        }
    }

    // --- softmax per px; reduce across the 4 tap groups (xor16, xor32)
    float pj[2][3];
#pragma unroll
    for (int px = 0; px < 2; px++) {
        float m = fmaxf(fmaxf(s[px][0], s[px][1]), s[px][2]);
        m = fmaxf(m, __shfl_xor(m, 16));
        m = fmaxf(m, __shfl_xor(m, 32));
        float e0 = __expf(s[px][0] - m);
        float e1 = __expf(s[px][1] - m);
        float e2 = __expf(s[px][2] - m);
        float sum = e0 + e1 + e2;
        sum += __shfl_xor(sum, 16);
        sum += __shfl_xor(sum, 32);
        float inv = __builtin_amdgcn_rcpf(sum);
        pj[px][0] = e0 * inv; pj[px][1] = e1 * inv; pj[px][2] = e2 * inv;
    }

    // --- value phase: 16B V loads (8 channels/lane), packed __hfma2 accumulation
    __half2 acc[2][4];
#pragma unroll
    for (int px = 0; px < 2; px++)
#pragma unroll
        for (int q = 0; q < 4; q++) acc[px][q] = __float2half2_rn(0.f);

#pragma unroll
    for (int px = 0; px < 2; px++) {
#pragma unroll
        for (int jj = 0; jj < 3; jj++) {
            int j = jj * 4 + jg;
            if (j < 9) {
                float p = pj[px][jj];
                float4 w = wts[wv][px][j];
                int4 co = cof[wv][px][j];
                float4 r0 = *(const float4*)(vb + (size_t)co.x * 128);
                float4 r1 = *(const float4*)(vb + (size_t)co.y * 128);
                float4 r2 = *(const float4*)(vb + (size_t)co.z * 128);
                float4 r3 = *(const float4*)(vb + (size_t)co.w * 128);
                const __half2* A0 = (const __half2*)&r0;
                const __half2* A1 = (const __half2*)&r1;
                const __half2* A2 = (const __half2*)&r2;
                const __half2* A3 = (const __half2*)&r3;
                __half2 f0 = __float2half2_rn(w.x * p);
                __half2 f1 = __float2half2_rn(w.y * p);
                __half2 f2 = __float2half2_rn(w.z * p);
                __half2 f3 = __float2half2_rn(w.w * p);
#pragma unroll
                for (int q = 0; q < 4; q++) {
                    acc[px][q] = __hfma2(f0, A0[q], acc[px][q]);
                    acc[px][q] = __hfma2(f1, A1[q], acc[px][q]);
                    acc[px][q] = __hfma2(f2, A2[q], acc[px][q]);
                    acc[px][q] = __hfma2(f3, A3[q], acc[px][q]);
                }
            }
        }
    }

    // --- output: cvt to float, reduce across tap groups in float, write LDS
#pragma unroll
    for (int px = 0; px < 2; px++) {
        float f[8];
#pragma unroll
        for (int q = 0; q < 4; q++) {
            float2 t = __half22float2(acc[px][q]);
            f[2 * q] = t.x; f[2 * q + 1] = t.y;
        }
#pragma unroll
        for (int i = 0; i < 8; i++) {
            f[i] += __shfl_xor(f[i], 16);
            f[i] += __shfl_xor(f[i], 32);
        }
        if (lane < 16) {
            *(float4*)&outb[wv][px][c2 * 8]     = make_float4(f[0], f[1], f[2], f[3]);
            *(float4*)&outb[wv][px][c2 * 8 + 4] = make_float4(f[4], f[5], f[6], f[7]);
        }
    }
    __syncthreads();

    // final write: thread t: ch = t&127, qh = t>>7 -> float4 covering px qh*4..qh*4+3
    {
        int ch = tid & 127, qh = tid >> 7;
        float* op = out + ((size_t)b * NC + g * 128 + ch) * N1 + p0 + qh * 4;
        float4 v4 = make_float4(outb[qh * 2][0][ch], outb[qh * 2][1][ch],
                                outb[qh * 2 + 1][0][ch], outb[qh * 2 + 1][1][ch]);
        *(float4*)op = v4;
    }
}

extern "C" void kernel_launch(void* const* d_in, const int* in_sizes, int n_in,
                              void* d_out, int out_size, void* d_ws, size_t ws_size,
                              hipStream_t stream) {
    const float* x      = (const float*)d_in[0];
    const float* ln_g   = (const float*)d_in[1];
    const float* ln_b   = (const float*)d_in[2];
    const float* Wq     = (const float*)d_in[3];
    const float* Wk     = (const float*)d_in[4];
    const float* dw_w   = (const float*)d_in[5];
    const float* off_g  = (const float*)d_in[6];
    const float* off_bt = (const float*)d_in[7];
    const float* off_w  = (const float*)d_in[8];
    const float* off_b  = (const float*)d_in[9];
    const float* rpb    = (const float*)d_in[10];
    float* out = (float*)d_out;

    // Workspace layout. fp32 region then fp16 region then qr. ~12 MB. NO aliasing.
    float* ws = (float*)d_ws;
    float* WT4    = ws;                       // 32768   [64][128][4]
    float* q_pix  = WT4 + 32768;              // 294912  [2][2304][64]
    float* pred   = q_pix + 294912;           // 663552  [4][9216][18]
    float* dwT    = pred + 663552;            // 288     [9][32]
    float* wg2    = dwT + 288;                // 6912    [8][288][3]
    float* bsg2   = wg2 + 6912;               // 24      [8][3]
    __half* v_nhwc = (__half*)(bsg2 + 24);    // 1179648 h [4][2304][128]
    __half* k_nhwc = v_nhwc + 1179648;        // 294912 h  [4][2304][32]
    float* qr      = (float*)(k_nhwc + 294912); // 1179648 f [2][9216][64]

    kA_prep<<<1309, 256, 0, stream>>>(x, Wq, Wk, off_w, dw_w, off_b,
                                      v_nhwc, WT4, dwT, wg2, bsg2);
    k1_ln_qk<<<576, 512, 0, stream>>>(v_nhwc, ln_g, ln_b, WT4, q_pix, k_nhwc);
    k34_t_pred<<<576, 512, 0, stream>>>(q_pix, dwT, off_g, off_bt, wg2, bsg2,
                                        qr, pred);
    k5_attn<<<4608, 256, 0, stream>>>(pred, qr, k_nhwc, v_nhwc, rpb, out);
}